// Round 1
// 1445.760 us; speedup vs baseline: 1.8598x; 1.8598x over previous
//
#include <hip/hip_runtime.h>
#include <cstddef>
#include <cstdint>

// Problem constants (match reference)
#define N_SRC1 1210000
#define N_DST1 110000
#define N_SRC2 110000
#define N_DST2 10000
#define E1 1100000
#define E2 100000
#define IN_DIM 128
#define HID_DIM 256
#define OUT_DIM 128

// ---------------- degree + dst-count accumulation ----------------
__global__ __launch_bounds__(256) void count_kernel(const int* __restrict__ src,
                                                    const int* __restrict__ dst,
                                                    float* __restrict__ outdeg,
                                                    int* __restrict__ cnt, int E) {
    int i = blockIdx.x * 256 + threadIdx.x;
    if (i < E) {
        unsafeAtomicAdd(&outdeg[src[i]], 1.0f);
        atomicAdd(&cnt[dst[i]], 1);
    }
}

// deg -> rsqrt(max(deg,1)) in place
__global__ __launch_bounds__(256) void rsqrt_kernel(float* __restrict__ p, int n) {
    int i = blockIdx.x * 256 + threadIdx.x;
    if (i < n) p[i] = rsqrtf(fmaxf(p[i], 1.0f));
}

// ---------------- single-block exclusive scan (counts -> offsets + cursor) ----------------
__global__ __launch_bounds__(1024) void scan_kernel(const int* __restrict__ cnt,
                                                    int* __restrict__ offs,
                                                    int* __restrict__ cursor, int n) {
    __shared__ int smem[1024];
    __shared__ int running;
    if (threadIdx.x == 0) running = 0;
    __syncthreads();
    for (int base = 0; base < n; base += 1024) {
        int i = base + threadIdx.x;
        int v = (i < n) ? cnt[i] : 0;
        smem[threadIdx.x] = v;
        __syncthreads();
        #pragma unroll
        for (int off = 1; off < 1024; off <<= 1) {
            int t = (threadIdx.x >= off) ? smem[threadIdx.x - off] : 0;
            __syncthreads();
            smem[threadIdx.x] += t;
            __syncthreads();
        }
        int excl = smem[threadIdx.x] - v + running;
        if (i < n) { offs[i] = excl; cursor[i] = excl; }
        __syncthreads();
        if (threadIdx.x == 0) running += smem[1023];
        __syncthreads();
    }
    if (threadIdx.x == 0) offs[n] = running;
}

// ---------------- bucket fill: edge src ids grouped by dst ----------------
__global__ __launch_bounds__(256) void fill_kernel(const int* __restrict__ src,
                                                   const int* __restrict__ dst,
                                                   int* __restrict__ cursor,
                                                   int* __restrict__ elist, int E) {
    int i = blockIdx.x * 256 + threadIdx.x;
    if (i < E) {
        int pos = atomicAdd(&cursor[dst[i]], 1);
        elist[pos] = src[i];
    }
}

// ---------------- layer-1 gather: one wave (64 lanes x float2) per dst row ----------------
// agg[d] = rsqrt(indeg[d]) * sum_{s in N(d)} feat[s] * rsqrt(outdeg[s])
__global__ __launch_bounds__(256) void gather1_kernel(const float* __restrict__ feat,
                                                      const int* __restrict__ elist,
                                                      const int* __restrict__ offs,
                                                      const float* __restrict__ rs_out,
                                                      float* __restrict__ agg, int n_dst) {
    int d = blockIdx.x * 4 + (threadIdx.x >> 6);
    if (d >= n_dst) return;
    int lane = threadIdx.x & 63;
    int beg = offs[d], end = offs[d + 1];
    float2 acc = make_float2(0.f, 0.f);
    for (int j = beg; j < end; ++j) {
        int s = elist[j];
        float sc = rs_out[s];
        float2 v = ((const float2*)(feat + (size_t)s * IN_DIM))[lane];
        acc.x += v.x * sc;
        acc.y += v.y * sc;
    }
    float rin = rsqrtf(fmaxf((float)(end - beg), 1.f));
    acc.x *= rin; acc.y *= rin;
    ((float2*)(agg + (size_t)d * IN_DIM))[lane] = acc;
}

// ---------------- layer-2 gather: one wave (64 lanes x float4) per dst row ----------------
__global__ __launch_bounds__(256) void gather2_kernel(const float* __restrict__ h1,
                                                      const int* __restrict__ elist,
                                                      const int* __restrict__ offs,
                                                      const float* __restrict__ rs_out,
                                                      float* __restrict__ agg, int n_dst) {
    int d = blockIdx.x * 4 + (threadIdx.x >> 6);
    if (d >= n_dst) return;
    int lane = threadIdx.x & 63;
    int beg = offs[d], end = offs[d + 1];
    float4 acc = make_float4(0.f, 0.f, 0.f, 0.f);
    for (int j = beg; j < end; ++j) {
        int s = elist[j];
        float sc = rs_out[s];
        float4 v = ((const float4*)(h1 + (size_t)s * HID_DIM))[lane];
        acc.x += v.x * sc;
        acc.y += v.y * sc;
        acc.z += v.z * sc;
        acc.w += v.w * sc;
    }
    float rin = rsqrtf(fmaxf((float)(end - beg), 1.f));
    acc.x *= rin; acc.y *= rin; acc.z *= rin; acc.w *= rin;
    ((float4*)(agg + (size_t)d * HID_DIM))[lane] = acc;
}

// ---------------- GEMM1 + bias + sigmoid gate ----------------
// C(110000x256) = agg1 @ W1 + b1 ; alpha=sigmoid(C@attn1); h1=C*alpha
// Block: 256 thr (4 waves), tile 32 rows x 256 cols. Thread: 8 rows x 4 cols.
// acc = 8 x float4 = 32 VGPRs; #pragma unroll 2 on k4 bounds B-operand hoisting.
// (Previous 16-rows/thread version spilled: VGPR=256, 3.9 GB scratch traffic.)
__global__ __launch_bounds__(256) void gemm1_gate(const float* __restrict__ agg,
                                                  const float* __restrict__ W,
                                                  const float* __restrict__ bias,
                                                  const float* __restrict__ attn,
                                                  float* __restrict__ h1, int M) {
    __shared__ float As[32][IN_DIM + 4];
    __shared__ float Bs[32][HID_DIM];
    const int t = threadIdx.x;
    const int row0 = blockIdx.x * 32;
    const int col = t & 63;         // *4 -> cols
    const int rbase = (t >> 6) * 8; // wave-uniform

    #pragma unroll
    for (int i = 0; i < 4; ++i) {
        int idx = t + i * 256;          // 0..1023 float4 slots (32 rows x 32 f4)
        int r = idx >> 5, c4 = idx & 31;
        int row = row0 + r;
        float4 v = make_float4(0.f, 0.f, 0.f, 0.f);
        if (row < M) v = ((const float4*)(agg + (size_t)row * IN_DIM))[c4];
        *(float4*)&As[r][c4 * 4] = v;
    }

    float4 acc[8];
    #pragma unroll
    for (int rr = 0; rr < 8; ++rr) acc[rr] = make_float4(0.f, 0.f, 0.f, 0.f);

    for (int kc = 0; kc < 4; ++kc) {   // K chunks of 32
        __syncthreads();
        #pragma unroll
        for (int i = 0; i < 8; ++i) {
            int idx = t + i * 256;      // 0..2047 float4 slots (32x64)
            int kk = idx >> 6, c4 = idx & 63;
            *(float4*)&Bs[kk][c4 * 4] = ((const float4*)(W + (size_t)(kc * 32 + kk) * HID_DIM))[c4];
        }
        __syncthreads();
        #pragma unroll 2
        for (int k4 = 0; k4 < 8; ++k4) {
            int kk = k4 * 4;
            float4 b0 = *(float4*)&Bs[kk + 0][col * 4];
            float4 b1v = *(float4*)&Bs[kk + 1][col * 4];
            float4 b2v = *(float4*)&Bs[kk + 2][col * 4];
            float4 b3v = *(float4*)&Bs[kk + 3][col * 4];
            int ka = kc * 32 + kk;
            #pragma unroll
            for (int rr = 0; rr < 8; ++rr) {
                float4 a = *(const float4*)&As[rbase + rr][ka];
                acc[rr].x += a.x * b0.x + a.y * b1v.x + a.z * b2v.x + a.w * b3v.x;
                acc[rr].y += a.x * b0.y + a.y * b1v.y + a.z * b2v.y + a.w * b3v.y;
                acc[rr].z += a.x * b0.z + a.y * b1v.z + a.z * b2v.z + a.w * b3v.z;
                acc[rr].w += a.x * b0.w + a.y * b1v.w + a.z * b2v.w + a.w * b3v.w;
            }
        }
    }

    float4 bb = *(const float4*)&bias[col * 4];
    float4 at = *(const float4*)&attn[col * 4];
    #pragma unroll
    for (int rr = 0; rr < 8; ++rr) {
        int row = row0 + rbase + rr;
        float4 v = acc[rr];
        v.x += bb.x; v.y += bb.y; v.z += bb.z; v.w += bb.w;
        float p = v.x * at.x + v.y * at.y + v.z * at.z + v.w * at.w;
        p += __shfl_down(p, 32);
        p += __shfl_down(p, 16);
        p += __shfl_down(p, 8);
        p += __shfl_down(p, 4);
        p += __shfl_down(p, 2);
        p += __shfl_down(p, 1);
        p = __shfl(p, 0);
        float alpha = 1.f / (1.f + expf(-p));
        v.x *= alpha; v.y *= alpha; v.z *= alpha; v.w *= alpha;
        if (row < M) *(float4*)&h1[(size_t)row * HID_DIM + col * 4] = v;
    }
}

// ---------------- GEMM2 + bias + sigmoid gate -> outputs ----------------
__global__ __launch_bounds__(256) void gemm2_gate(const float* __restrict__ agg,
                                                  const float* __restrict__ W,
                                                  const float* __restrict__ bias,
                                                  const float* __restrict__ attn,
                                                  float* __restrict__ out_h,
                                                  float* __restrict__ out_alpha, int M) {
    __shared__ float As[32][HID_DIM + 4];
    __shared__ float Bs[32][OUT_DIM];
    const int t = threadIdx.x;
    const int row0 = blockIdx.x * 32;
    const int col = t & 63;         // *2 -> cols
    const int rbase = (t >> 6) * 8; // wave-uniform

    #pragma unroll
    for (int i = 0; i < 8; ++i) {
        int idx = t + i * 256;       // 0..2047 float4 slots (32x64)
        int r = idx >> 6, c4 = idx & 63;
        int row = row0 + r;
        float4 v = make_float4(0.f, 0.f, 0.f, 0.f);
        if (row < M) v = ((const float4*)(agg + (size_t)row * HID_DIM))[c4];
        *(float4*)&As[r][c4 * 4] = v;
    }

    float2 acc[8];
    #pragma unroll
    for (int rr = 0; rr < 8; ++rr) acc[rr] = make_float2(0.f, 0.f);

    for (int kc = 0; kc < 8; ++kc) {   // K=256, chunks of 32
        __syncthreads();
        #pragma unroll
        for (int i = 0; i < 4; ++i) {
            int idx = t + i * 256;      // 0..1023 float4 slots (32x32)
            int kk = idx >> 5, c4 = idx & 31;
            *(float4*)&Bs[kk][c4 * 4] = ((const float4*)(W + (size_t)(kc * 32 + kk) * OUT_DIM))[c4];
        }
        __syncthreads();
        #pragma unroll
        for (int k4 = 0; k4 < 8; ++k4) {
            int kk = k4 * 4;
            float2 b0 = *(float2*)&Bs[kk + 0][col * 2];
            float2 b1v = *(float2*)&Bs[kk + 1][col * 2];
            float2 b2v = *(float2*)&Bs[kk + 2][col * 2];
            float2 b3v = *(float2*)&Bs[kk + 3][col * 2];
            int ka = kc * 32 + kk;
            #pragma unroll
            for (int rr = 0; rr < 8; ++rr) {
                float4 a = *(const float4*)&As[rbase + rr][ka];
                acc[rr].x += a.x * b0.x + a.y * b1v.x + a.z * b2v.x + a.w * b3v.x;
                acc[rr].y += a.x * b0.y + a.y * b1v.y + a.z * b2v.y + a.w * b3v.y;
            }
        }
    }

    float2 bb = *(const float2*)&bias[col * 2];
    float2 at = *(const float2*)&attn[col * 2];
    #pragma unroll
    for (int rr = 0; rr < 8; ++rr) {
        int row = row0 + rbase + rr;
        float2 v = acc[rr];
        v.x += bb.x; v.y += bb.y;
        float p = v.x * at.x + v.y * at.y;
        p += __shfl_down(p, 32);
        p += __shfl_down(p, 16);
        p += __shfl_down(p, 8);
        p += __shfl_down(p, 4);
        p += __shfl_down(p, 2);
        p += __shfl_down(p, 1);
        p = __shfl(p, 0);
        float alpha = 1.f / (1.f + expf(-p));
        v.x *= alpha; v.y *= alpha;
        if (row < M) {
            *(float2*)&out_h[(size_t)row * OUT_DIM + col * 2] = v;
            if (col == 0) out_alpha[row] = alpha;
        }
    }
}

extern "C" void kernel_launch(void* const* d_in, const int* in_sizes, int n_in,
                              void* d_out, int out_size, void* d_ws, size_t ws_size,
                              hipStream_t stream) {
    const float* feat  = (const float*)d_in[0];
    const float* W1    = (const float*)d_in[1];
    const float* b1    = (const float*)d_in[2];
    const float* attn1 = (const float*)d_in[3];
    const float* W2    = (const float*)d_in[4];
    const float* b2    = (const float*)d_in[5];
    const float* attn2 = (const float*)d_in[6];
    const int* src1 = (const int*)d_in[7];
    const int* dst1 = (const int*)d_in[8];
    const int* src2 = (const int*)d_in[9];
    const int* dst2 = (const int*)d_in[10];
    float* out = (float*)d_out;

    // workspace layout
    float* ws = (float*)d_ws;
    float* outdeg1 = ws;                                   // N_SRC1 (zeroed)
    float* outdeg2 = outdeg1 + N_SRC1;                     // N_SRC2 (zeroed)
    int*   cnt1    = (int*)(outdeg2 + N_SRC2);             // N_DST1 (zeroed)
    int*   cnt2    = cnt1 + N_DST1;                        // N_DST2 (zeroed)
    int*   offs1   = cnt2 + N_DST2;                        // N_DST1+1
    int*   cursor1 = offs1 + N_DST1 + 1;                   // N_DST1
    int*   offs2   = cursor1 + N_DST1;                     // N_DST2+1
    int*   cursor2 = offs2 + N_DST2 + 1;                   // N_DST2
    int*   elist1  = cursor2 + N_DST2;                     // E1
    int*   elist2  = elist1 + E1;                          // E2
    float* agg1    = (float*)(elist2 + E2);                // N_DST1*IN_DIM
    float* agg2    = agg1 + (size_t)N_DST1 * IN_DIM;       // N_DST2*HID_DIM
    float* h1      = agg2 + (size_t)N_DST2 * HID_DIM;      // N_DST1*HID_DIM

    // zero only the atomic-accumulated arrays (outdeg1, outdeg2, cnt1, cnt2 contiguous)
    const size_t zero_bytes = ((size_t)N_SRC1 + N_SRC2 + N_DST1 + N_DST2) * 4;
    hipMemsetAsync(d_ws, 0, zero_bytes, stream);

    count_kernel<<<(E1 + 255) / 256, 256, 0, stream>>>(src1, dst1, outdeg1, cnt1, E1);
    count_kernel<<<(E2 + 255) / 256, 256, 0, stream>>>(src2, dst2, outdeg2, cnt2, E2);
    rsqrt_kernel<<<(N_SRC1 + N_SRC2 + 255) / 256, 256, 0, stream>>>(outdeg1, N_SRC1 + N_SRC2);

    scan_kernel<<<1, 1024, 0, stream>>>(cnt1, offs1, cursor1, N_DST1);
    scan_kernel<<<1, 1024, 0, stream>>>(cnt2, offs2, cursor2, N_DST2);
    fill_kernel<<<(E1 + 255) / 256, 256, 0, stream>>>(src1, dst1, cursor1, elist1, E1);
    fill_kernel<<<(E2 + 255) / 256, 256, 0, stream>>>(src2, dst2, cursor2, elist2, E2);

    gather1_kernel<<<(N_DST1 + 3) / 4, 256, 0, stream>>>(feat, elist1, offs1, outdeg1, agg1, N_DST1);
    gemm1_gate<<<(N_DST1 + 31) / 32, 256, 0, stream>>>(agg1, W1, b1, attn1, h1, N_DST1);
    gather2_kernel<<<(N_DST2 + 3) / 4, 256, 0, stream>>>(h1, elist2, offs2, outdeg2, agg2, N_DST2);
    gemm2_gate<<<(N_DST2 + 31) / 32, 256, 0, stream>>>(agg2, W2, b2, attn2,
                                                       out, out + (size_t)N_DST2 * OUT_DIM, N_DST2);
}

// Round 2
// 1246.847 us; speedup vs baseline: 2.1565x; 1.1595x over previous
//
#include <hip/hip_runtime.h>
#include <cstddef>
#include <cstdint>

// Problem constants (match reference)
#define N_SRC1 1210000
#define N_DST1 110000
#define N_SRC2 110000
#define N_DST2 10000
#define E1 1100000
#define E2 100000
#define IN_DIM 128
#define HID_DIM 256
#define OUT_DIM 128

// ---------------- degree + dst-count accumulation ----------------
__global__ __launch_bounds__(256) void count_kernel(const int* __restrict__ src,
                                                    const int* __restrict__ dst,
                                                    float* __restrict__ outdeg,
                                                    int* __restrict__ cnt, int E) {
    int i = blockIdx.x * 256 + threadIdx.x;
    if (i < E) {
        unsafeAtomicAdd(&outdeg[src[i]], 1.0f);
        atomicAdd(&cnt[dst[i]], 1);
    }
}

// deg -> rsqrt(max(deg,1)) in place
__global__ __launch_bounds__(256) void rsqrt_kernel(float* __restrict__ p, int n) {
    int i = blockIdx.x * 256 + threadIdx.x;
    if (i < n) p[i] = rsqrtf(fmaxf(p[i], 1.0f));
}

// ---------------- device-wide exclusive scan, 3 phases ----------------
// (replaces the single-block serial scan: 108 serial iterations on 1 CU ~ 200-400 us)
// P1: per-block inclusive scan -> block-local exclusive offsets + block sum
__global__ __launch_bounds__(1024) void scan_part(const int* __restrict__ cnt,
                                                  int* __restrict__ offs,
                                                  int* __restrict__ bsum, int n) {
    __shared__ int smem[1024];
    int i = blockIdx.x * 1024 + threadIdx.x;
    int v = (i < n) ? cnt[i] : 0;
    smem[threadIdx.x] = v;
    __syncthreads();
    #pragma unroll
    for (int off = 1; off < 1024; off <<= 1) {
        int t = (threadIdx.x >= off) ? smem[threadIdx.x - off] : 0;
        __syncthreads();
        smem[threadIdx.x] += t;
        __syncthreads();
    }
    if (i < n) offs[i] = smem[threadIdx.x] - v;      // block-local exclusive
    if (threadIdx.x == 1023) bsum[blockIdx.x] = smem[1023];
}

// P2: scan the block sums (nb <= 1024) in one block; write grand total to offs[n]
__global__ __launch_bounds__(1024) void scan_bsum(int* __restrict__ bsum,
                                                  int* __restrict__ offs_end, int nb) {
    __shared__ int smem[1024];
    int v = (threadIdx.x < nb) ? bsum[threadIdx.x] : 0;
    smem[threadIdx.x] = v;
    __syncthreads();
    #pragma unroll
    for (int off = 1; off < 1024; off <<= 1) {
        int t = (threadIdx.x >= off) ? smem[threadIdx.x - off] : 0;
        __syncthreads();
        smem[threadIdx.x] += t;
        __syncthreads();
    }
    if (threadIdx.x < nb) bsum[threadIdx.x] = smem[threadIdx.x] - v;  // exclusive
    if (threadIdx.x == nb - 1) *offs_end = smem[threadIdx.x];         // grand total
}

// P3: add scanned block sums back; also init cursor
__global__ __launch_bounds__(1024) void scan_add(int* __restrict__ offs,
                                                 int* __restrict__ cursor,
                                                 const int* __restrict__ bsum, int n) {
    int i = blockIdx.x * 1024 + threadIdx.x;
    if (i < n) {
        int o = offs[i] + bsum[blockIdx.x];
        offs[i] = o;
        cursor[i] = o;
    }
}

// ---------------- bucket fill: edge src ids grouped by dst ----------------
__global__ __launch_bounds__(256) void fill_kernel(const int* __restrict__ src,
                                                   const int* __restrict__ dst,
                                                   int* __restrict__ cursor,
                                                   int* __restrict__ elist, int E) {
    int i = blockIdx.x * 256 + threadIdx.x;
    if (i < E) {
        int pos = atomicAdd(&cursor[dst[i]], 1);
        elist[pos] = src[i];
    }
}

// ---------------- layer-1 gather: one wave (64 lanes x float2) per dst row ----------------
// agg[d] = rsqrt(indeg[d]) * sum_{s in N(d)} feat[s] * rsqrt(outdeg[s])
__global__ __launch_bounds__(256) void gather1_kernel(const float* __restrict__ feat,
                                                      const int* __restrict__ elist,
                                                      const int* __restrict__ offs,
                                                      const float* __restrict__ rs_out,
                                                      float* __restrict__ agg, int n_dst) {
    int d = blockIdx.x * 4 + (threadIdx.x >> 6);
    if (d >= n_dst) return;
    int lane = threadIdx.x & 63;
    int beg = offs[d], end = offs[d + 1];
    float2 acc = make_float2(0.f, 0.f);
    for (int j = beg; j < end; ++j) {
        int s = elist[j];
        float sc = rs_out[s];
        float2 v = ((const float2*)(feat + (size_t)s * IN_DIM))[lane];
        acc.x += v.x * sc;
        acc.y += v.y * sc;
    }
    float rin = rsqrtf(fmaxf((float)(end - beg), 1.f));
    acc.x *= rin; acc.y *= rin;
    ((float2*)(agg + (size_t)d * IN_DIM))[lane] = acc;
}

// ---------------- layer-2 gather: one wave (64 lanes x float4) per dst row ----------------
__global__ __launch_bounds__(256) void gather2_kernel(const float* __restrict__ h1,
                                                      const int* __restrict__ elist,
                                                      const int* __restrict__ offs,
                                                      const float* __restrict__ rs_out,
                                                      float* __restrict__ agg, int n_dst) {
    int d = blockIdx.x * 4 + (threadIdx.x >> 6);
    if (d >= n_dst) return;
    int lane = threadIdx.x & 63;
    int beg = offs[d], end = offs[d + 1];
    float4 acc = make_float4(0.f, 0.f, 0.f, 0.f);
    for (int j = beg; j < end; ++j) {
        int s = elist[j];
        float sc = rs_out[s];
        float4 v = ((const float4*)(h1 + (size_t)s * HID_DIM))[lane];
        acc.x += v.x * sc;
        acc.y += v.y * sc;
        acc.z += v.z * sc;
        acc.w += v.w * sc;
    }
    float rin = rsqrtf(fmaxf((float)(end - beg), 1.f));
    acc.x *= rin; acc.y *= rin; acc.z *= rin; acc.w *= rin;
    ((float4*)(agg + (size_t)d * HID_DIM))[lane] = acc;
}

// ---------------- GEMM1 + bias + sigmoid gate ----------------
// C(110000x256) = agg1 @ W1 + b1 ; alpha=sigmoid(C@attn1); h1=C*alpha
// Block: 256 thr (4 waves), tile 32 rows x 256 cols. Thread: 8 rows x 4 cols.
// acc = 8 x float4 = 32 VGPRs; #pragma unroll 2 on k4 bounds B-operand hoisting.
// (16 rows/thread spilled: VGPR=256, 3.9 GB scratch traffic, 1390 us.)
__global__ __launch_bounds__(256) void gemm1_gate(const float* __restrict__ agg,
                                                  const float* __restrict__ W,
                                                  const float* __restrict__ bias,
                                                  const float* __restrict__ attn,
                                                  float* __restrict__ h1, int M) {
    __shared__ float As[32][IN_DIM + 4];
    __shared__ float Bs[32][HID_DIM];
    const int t = threadIdx.x;
    const int row0 = blockIdx.x * 32;
    const int col = t & 63;         // *4 -> cols
    const int rbase = (t >> 6) * 8; // wave-uniform

    #pragma unroll
    for (int i = 0; i < 4; ++i) {
        int idx = t + i * 256;          // 0..1023 float4 slots (32 rows x 32 f4)
        int r = idx >> 5, c4 = idx & 31;
        int row = row0 + r;
        float4 v = make_float4(0.f, 0.f, 0.f, 0.f);
        if (row < M) v = ((const float4*)(agg + (size_t)row * IN_DIM))[c4];
        *(float4*)&As[r][c4 * 4] = v;
    }

    float4 acc[8];
    #pragma unroll
    for (int rr = 0; rr < 8; ++rr) acc[rr] = make_float4(0.f, 0.f, 0.f, 0.f);

    for (int kc = 0; kc < 4; ++kc) {   // K chunks of 32
        __syncthreads();
        #pragma unroll
        for (int i = 0; i < 8; ++i) {
            int idx = t + i * 256;      // 0..2047 float4 slots (32x64)
            int kk = idx >> 6, c4 = idx & 63;
            *(float4*)&Bs[kk][c4 * 4] = ((const float4*)(W + (size_t)(kc * 32 + kk) * HID_DIM))[c4];
        }
        __syncthreads();
        #pragma unroll 2
        for (int k4 = 0; k4 < 8; ++k4) {
            int kk = k4 * 4;
            float4 b0 = *(float4*)&Bs[kk + 0][col * 4];
            float4 b1v = *(float4*)&Bs[kk + 1][col * 4];
            float4 b2v = *(float4*)&Bs[kk + 2][col * 4];
            float4 b3v = *(float4*)&Bs[kk + 3][col * 4];
            int ka = kc * 32 + kk;
            #pragma unroll
            for (int rr = 0; rr < 8; ++rr) {
                float4 a = *(const float4*)&As[rbase + rr][ka];
                acc[rr].x += a.x * b0.x + a.y * b1v.x + a.z * b2v.x + a.w * b3v.x;
                acc[rr].y += a.x * b0.y + a.y * b1v.y + a.z * b2v.y + a.w * b3v.y;
                acc[rr].z += a.x * b0.z + a.y * b1v.z + a.z * b2v.z + a.w * b3v.z;
                acc[rr].w += a.x * b0.w + a.y * b1v.w + a.z * b2v.w + a.w * b3v.w;
            }
        }
    }

    float4 bb = *(const float4*)&bias[col * 4];
    float4 at = *(const float4*)&attn[col * 4];
    #pragma unroll
    for (int rr = 0; rr < 8; ++rr) {
        int row = row0 + rbase + rr;
        float4 v = acc[rr];
        v.x += bb.x; v.y += bb.y; v.z += bb.z; v.w += bb.w;
        float p = v.x * at.x + v.y * at.y + v.z * at.z + v.w * at.w;
        p += __shfl_down(p, 32);
        p += __shfl_down(p, 16);
        p += __shfl_down(p, 8);
        p += __shfl_down(p, 4);
        p += __shfl_down(p, 2);
        p += __shfl_down(p, 1);
        p = __shfl(p, 0);
        float alpha = 1.f / (1.f + expf(-p));
        v.x *= alpha; v.y *= alpha; v.z *= alpha; v.w *= alpha;
        if (row < M) *(float4*)&h1[(size_t)row * HID_DIM + col * 4] = v;
    }
}

// ---------------- GEMM2 + bias + sigmoid gate -> outputs ----------------
__global__ __launch_bounds__(256) void gemm2_gate(const float* __restrict__ agg,
                                                  const float* __restrict__ W,
                                                  const float* __restrict__ bias,
                                                  const float* __restrict__ attn,
                                                  float* __restrict__ out_h,
                                                  float* __restrict__ out_alpha, int M) {
    __shared__ float As[32][HID_DIM + 4];
    __shared__ float Bs[32][OUT_DIM];
    const int t = threadIdx.x;
    const int row0 = blockIdx.x * 32;
    const int col = t & 63;         // *2 -> cols
    const int rbase = (t >> 6) * 8; // wave-uniform

    #pragma unroll
    for (int i = 0; i < 8; ++i) {
        int idx = t + i * 256;       // 0..2047 float4 slots (32x64)
        int r = idx >> 6, c4 = idx & 63;
        int row = row0 + r;
        float4 v = make_float4(0.f, 0.f, 0.f, 0.f);
        if (row < M) v = ((const float4*)(agg + (size_t)row * HID_DIM))[c4];
        *(float4*)&As[r][c4 * 4] = v;
    }

    float2 acc[8];
    #pragma unroll
    for (int rr = 0; rr < 8; ++rr) acc[rr] = make_float2(0.f, 0.f);

    for (int kc = 0; kc < 8; ++kc) {   // K=256, chunks of 32
        __syncthreads();
        #pragma unroll
        for (int i = 0; i < 4; ++i) {
            int idx = t + i * 256;      // 0..1023 float4 slots (32x32)
            int kk = idx >> 5, c4 = idx & 31;
            *(float4*)&Bs[kk][c4 * 4] = ((const float4*)(W + (size_t)(kc * 32 + kk) * OUT_DIM))[c4];
        }
        __syncthreads();
        #pragma unroll
        for (int k4 = 0; k4 < 8; ++k4) {
            int kk = k4 * 4;
            float2 b0 = *(float2*)&Bs[kk + 0][col * 2];
            float2 b1v = *(float2*)&Bs[kk + 1][col * 2];
            float2 b2v = *(float2*)&Bs[kk + 2][col * 2];
            float2 b3v = *(float2*)&Bs[kk + 3][col * 2];
            int ka = kc * 32 + kk;
            #pragma unroll
            for (int rr = 0; rr < 8; ++rr) {
                float4 a = *(const float4*)&As[rbase + rr][ka];
                acc[rr].x += a.x * b0.x + a.y * b1v.x + a.z * b2v.x + a.w * b3v.x;
                acc[rr].y += a.x * b0.y + a.y * b1v.y + a.z * b2v.y + a.w * b3v.y;
            }
        }
    }

    float2 bb = *(const float2*)&bias[col * 2];
    float2 at = *(const float2*)&attn[col * 2];
    #pragma unroll
    for (int rr = 0; rr < 8; ++rr) {
        int row = row0 + rbase + rr;
        float2 v = acc[rr];
        v.x += bb.x; v.y += bb.y;
        float p = v.x * at.x + v.y * at.y;
        p += __shfl_down(p, 32);
        p += __shfl_down(p, 16);
        p += __shfl_down(p, 8);
        p += __shfl_down(p, 4);
        p += __shfl_down(p, 2);
        p += __shfl_down(p, 1);
        p = __shfl(p, 0);
        float alpha = 1.f / (1.f + expf(-p));
        v.x *= alpha; v.y *= alpha;
        if (row < M) {
            *(float2*)&out_h[(size_t)row * OUT_DIM + col * 2] = v;
            if (col == 0) out_alpha[row] = alpha;
        }
    }
}

extern "C" void kernel_launch(void* const* d_in, const int* in_sizes, int n_in,
                              void* d_out, int out_size, void* d_ws, size_t ws_size,
                              hipStream_t stream) {
    const float* feat  = (const float*)d_in[0];
    const float* W1    = (const float*)d_in[1];
    const float* b1    = (const float*)d_in[2];
    const float* attn1 = (const float*)d_in[3];
    const float* W2    = (const float*)d_in[4];
    const float* b2    = (const float*)d_in[5];
    const float* attn2 = (const float*)d_in[6];
    const int* src1 = (const int*)d_in[7];
    const int* dst1 = (const int*)d_in[8];
    const int* src2 = (const int*)d_in[9];
    const int* dst2 = (const int*)d_in[10];
    float* out = (float*)d_out;

    // workspace layout
    float* ws = (float*)d_ws;
    float* outdeg1 = ws;                                   // N_SRC1 (zeroed)
    float* outdeg2 = outdeg1 + N_SRC1;                     // N_SRC2 (zeroed)
    int*   cnt1    = (int*)(outdeg2 + N_SRC2);             // N_DST1 (zeroed)
    int*   cnt2    = cnt1 + N_DST1;                        // N_DST2 (zeroed)
    int*   offs1   = cnt2 + N_DST2;                        // N_DST1+1
    int*   cursor1 = offs1 + N_DST1 + 1;                   // N_DST1
    int*   offs2   = cursor1 + N_DST1;                     // N_DST2+1
    int*   cursor2 = offs2 + N_DST2 + 1;                   // N_DST2
    int*   elist1  = cursor2 + N_DST2;                     // E1
    int*   elist2  = elist1 + E1;                          // E2
    float* agg1    = (float*)(elist2 + E2);                // N_DST1*IN_DIM
    float* agg2    = agg1 + (size_t)N_DST1 * IN_DIM;       // N_DST2*HID_DIM
    float* h1      = agg2 + (size_t)N_DST2 * HID_DIM;      // N_DST1*HID_DIM
    int*   bsum1   = (int*)(h1 + (size_t)N_DST1 * HID_DIM); // 128 block sums
    int*   bsum2   = bsum1 + 128;                          // 16 block sums

    // zero only the atomic-accumulated arrays (outdeg1, outdeg2, cnt1, cnt2 contiguous)
    const size_t zero_bytes = ((size_t)N_SRC1 + N_SRC2 + N_DST1 + N_DST2) * 4;
    hipMemsetAsync(d_ws, 0, zero_bytes, stream);

    count_kernel<<<(E1 + 255) / 256, 256, 0, stream>>>(src1, dst1, outdeg1, cnt1, E1);
    count_kernel<<<(E2 + 255) / 256, 256, 0, stream>>>(src2, dst2, outdeg2, cnt2, E2);
    rsqrt_kernel<<<(N_SRC1 + N_SRC2 + 255) / 256, 256, 0, stream>>>(outdeg1, N_SRC1 + N_SRC2);

    // device-wide 3-phase scans (was: 1-block serial scan, ~200-400 us on 1 CU)
    const int nb1 = (N_DST1 + 1023) / 1024;   // 108
    const int nb2 = (N_DST2 + 1023) / 1024;   // 10
    scan_part<<<nb1, 1024, 0, stream>>>(cnt1, offs1, bsum1, N_DST1);
    scan_bsum<<<1, 1024, 0, stream>>>(bsum1, offs1 + N_DST1, nb1);
    scan_add<<<nb1, 1024, 0, stream>>>(offs1, cursor1, bsum1, N_DST1);
    scan_part<<<nb2, 1024, 0, stream>>>(cnt2, offs2, bsum2, N_DST2);
    scan_bsum<<<1, 1024, 0, stream>>>(bsum2, offs2 + N_DST2, nb2);
    scan_add<<<nb2, 1024, 0, stream>>>(offs2, cursor2, bsum2, N_DST2);

    fill_kernel<<<(E1 + 255) / 256, 256, 0, stream>>>(src1, dst1, cursor1, elist1, E1);
    fill_kernel<<<(E2 + 255) / 256, 256, 0, stream>>>(src2, dst2, cursor2, elist2, E2);

    gather1_kernel<<<(N_DST1 + 3) / 4, 256, 0, stream>>>(feat, elist1, offs1, outdeg1, agg1, N_DST1);
    gemm1_gate<<<(N_DST1 + 31) / 32, 256, 0, stream>>>(agg1, W1, b1, attn1, h1, N_DST1);
    gather2_kernel<<<(N_DST2 + 3) / 4, 256, 0, stream>>>(h1, elist2, offs2, outdeg2, agg2, N_DST2);
    gemm2_gate<<<(N_DST2 + 31) / 32, 256, 0, stream>>>(agg2, W2, b2, attn2,
                                                       out, out + (size_t)N_DST2 * OUT_DIM, N_DST2);
}

// Round 3
// 1170.636 us; speedup vs baseline: 2.2969x; 1.0651x over previous
//
#include <hip/hip_runtime.h>
#include <cstddef>
#include <cstdint>

// Problem constants (match reference)
#define N_SRC1 1210000
#define N_DST1 110000
#define N_SRC2 110000
#define N_DST2 10000
#define E1 1100000
#define E2 100000
#define IN_DIM 128
#define HID_DIM 256
#define OUT_DIM 128

// ---------------- degree + dst-count accumulation ----------------
__global__ __launch_bounds__(256) void count_kernel(const int* __restrict__ src,
                                                    const int* __restrict__ dst,
                                                    float* __restrict__ outdeg,
                                                    int* __restrict__ cnt, int E) {
    int i = blockIdx.x * 256 + threadIdx.x;
    if (i < E) {
        unsafeAtomicAdd(&outdeg[src[i]], 1.0f);
        atomicAdd(&cnt[dst[i]], 1);
    }
}

// deg -> rsqrt(max(deg,1)) in place
__global__ __launch_bounds__(256) void rsqrt_kernel(float* __restrict__ p, int n) {
    int i = blockIdx.x * 256 + threadIdx.x;
    if (i < n) p[i] = rsqrtf(fmaxf(p[i], 1.0f));
}

// ---------------- device-wide exclusive scan, 3 phases ----------------
// P1: per-block inclusive scan -> block-local exclusive offsets + block sum
__global__ __launch_bounds__(1024) void scan_part(const int* __restrict__ cnt,
                                                  int* __restrict__ offs,
                                                  int* __restrict__ bsum, int n) {
    __shared__ int smem[1024];
    int i = blockIdx.x * 1024 + threadIdx.x;
    int v = (i < n) ? cnt[i] : 0;
    smem[threadIdx.x] = v;
    __syncthreads();
    #pragma unroll
    for (int off = 1; off < 1024; off <<= 1) {
        int t = (threadIdx.x >= off) ? smem[threadIdx.x - off] : 0;
        __syncthreads();
        smem[threadIdx.x] += t;
        __syncthreads();
    }
    if (i < n) offs[i] = smem[threadIdx.x] - v;      // block-local exclusive
    if (threadIdx.x == 1023) bsum[blockIdx.x] = smem[1023];
}

// P2: scan the block sums (nb <= 1024) in one block; write grand total to offs[n]
__global__ __launch_bounds__(1024) void scan_bsum(int* __restrict__ bsum,
                                                  int* __restrict__ offs_end, int nb) {
    __shared__ int smem[1024];
    int v = (threadIdx.x < nb) ? bsum[threadIdx.x] : 0;
    smem[threadIdx.x] = v;
    __syncthreads();
    #pragma unroll
    for (int off = 1; off < 1024; off <<= 1) {
        int t = (threadIdx.x >= off) ? smem[threadIdx.x - off] : 0;
        __syncthreads();
        smem[threadIdx.x] += t;
        __syncthreads();
    }
    if (threadIdx.x < nb) bsum[threadIdx.x] = smem[threadIdx.x] - v;  // exclusive
    if (threadIdx.x == nb - 1) *offs_end = smem[threadIdx.x];         // grand total
}

// P3: add scanned block sums back; also init cursor
__global__ __launch_bounds__(1024) void scan_add(int* __restrict__ offs,
                                                 int* __restrict__ cursor,
                                                 const int* __restrict__ bsum, int n) {
    int i = blockIdx.x * 1024 + threadIdx.x;
    if (i < n) {
        int o = offs[i] + bsum[blockIdx.x];
        offs[i] = o;
        cursor[i] = o;
    }
}

// ---------------- bucket fill: edge src ids grouped by dst ----------------
__global__ __launch_bounds__(256) void fill_kernel(const int* __restrict__ src,
                                                   const int* __restrict__ dst,
                                                   int* __restrict__ cursor,
                                                   int* __restrict__ elist, int E) {
    int i = blockIdx.x * 256 + threadIdx.x;
    if (i < E) {
        int pos = atomicAdd(&cursor[dst[i]], 1);
        elist[pos] = src[i];
    }
}

// ---------------- layer-1 gather: one wave (64 lanes x float2) per dst row ----------------
// agg[d] = rsqrt(indeg[d]) * sum_{s in N(d)} feat[s] * rsqrt(outdeg[s])
// Edge loop pipelined 4-deep: 4 independent feat-row loads in flight per wave
// (serial dependent chain was ~900cy HBM latency per edge).
__global__ __launch_bounds__(256) void gather1_kernel(const float* __restrict__ feat,
                                                      const int* __restrict__ elist,
                                                      const int* __restrict__ offs,
                                                      const float* __restrict__ rs_out,
                                                      float* __restrict__ agg, int n_dst) {
    int d = blockIdx.x * 4 + (threadIdx.x >> 6);
    if (d >= n_dst) return;
    int lane = threadIdx.x & 63;
    int beg = offs[d], end = offs[d + 1];
    float2 acc = make_float2(0.f, 0.f);
    int j = beg;
    for (; j + 4 <= end; j += 4) {
        int s0 = elist[j + 0];
        int s1 = elist[j + 1];
        int s2 = elist[j + 2];
        int s3 = elist[j + 3];
        float c0 = rs_out[s0], c1 = rs_out[s1], c2 = rs_out[s2], c3 = rs_out[s3];
        float2 v0 = ((const float2*)(feat + (size_t)s0 * IN_DIM))[lane];
        float2 v1 = ((const float2*)(feat + (size_t)s1 * IN_DIM))[lane];
        float2 v2 = ((const float2*)(feat + (size_t)s2 * IN_DIM))[lane];
        float2 v3 = ((const float2*)(feat + (size_t)s3 * IN_DIM))[lane];
        acc.x += v0.x * c0 + v1.x * c1 + v2.x * c2 + v3.x * c3;
        acc.y += v0.y * c0 + v1.y * c1 + v2.y * c2 + v3.y * c3;
    }
    for (; j < end; ++j) {
        int s = elist[j];
        float sc = rs_out[s];
        float2 v = ((const float2*)(feat + (size_t)s * IN_DIM))[lane];
        acc.x += v.x * sc;
        acc.y += v.y * sc;
    }
    float rin = rsqrtf(fmaxf((float)(end - beg), 1.f));
    acc.x *= rin; acc.y *= rin;
    ((float2*)(agg + (size_t)d * IN_DIM))[lane] = acc;
}

// ---------------- layer-2 gather: one wave (64 lanes x float4) per dst row ----------------
__global__ __launch_bounds__(256) void gather2_kernel(const float* __restrict__ h1,
                                                      const int* __restrict__ elist,
                                                      const int* __restrict__ offs,
                                                      const float* __restrict__ rs_out,
                                                      float* __restrict__ agg, int n_dst) {
    int d = blockIdx.x * 4 + (threadIdx.x >> 6);
    if (d >= n_dst) return;
    int lane = threadIdx.x & 63;
    int beg = offs[d], end = offs[d + 1];
    float4 acc = make_float4(0.f, 0.f, 0.f, 0.f);
    int j = beg;
    for (; j + 4 <= end; j += 4) {
        int s0 = elist[j + 0];
        int s1 = elist[j + 1];
        int s2 = elist[j + 2];
        int s3 = elist[j + 3];
        float c0 = rs_out[s0], c1 = rs_out[s1], c2 = rs_out[s2], c3 = rs_out[s3];
        float4 v0 = ((const float4*)(h1 + (size_t)s0 * HID_DIM))[lane];
        float4 v1 = ((const float4*)(h1 + (size_t)s1 * HID_DIM))[lane];
        float4 v2 = ((const float4*)(h1 + (size_t)s2 * HID_DIM))[lane];
        float4 v3 = ((const float4*)(h1 + (size_t)s3 * HID_DIM))[lane];
        acc.x += v0.x * c0 + v1.x * c1 + v2.x * c2 + v3.x * c3;
        acc.y += v0.y * c0 + v1.y * c1 + v2.y * c2 + v3.y * c3;
        acc.z += v0.z * c0 + v1.z * c1 + v2.z * c2 + v3.z * c3;
        acc.w += v0.w * c0 + v1.w * c1 + v2.w * c2 + v3.w * c3;
    }
    for (; j < end; ++j) {
        int s = elist[j];
        float sc = rs_out[s];
        float4 v = ((const float4*)(h1 + (size_t)s * HID_DIM))[lane];
        acc.x += v.x * sc;
        acc.y += v.y * sc;
        acc.z += v.z * sc;
        acc.w += v.w * sc;
    }
    float rin = rsqrtf(fmaxf((float)(end - beg), 1.f));
    acc.x *= rin; acc.y *= rin; acc.z *= rin; acc.w *= rin;
    ((float4*)(agg + (size_t)d * HID_DIM))[lane] = acc;
}

// ---------------- GEMM1 + bias + sigmoid gate ----------------
// C(110000x256) = agg1 @ W1 + b1 ; alpha=sigmoid(C@attn1); h1=C*alpha
// Block: 512 thr (8 waves), tile 64 rows x 256 cols. Thread: 8 rows x 4 cols.
// 64-row tile halves W1-reload traffic + barriers per output row vs 32-row.
// acc = 32 VGPRs; unroll 2 bounds B hoisting (full unroll at 16 rows spilled: 3.9GB scratch).
// LDS = 66560 B (proven launchable in round 0) -> 2 blocks/CU.
__global__ __launch_bounds__(512) void gemm1_gate(const float* __restrict__ agg,
                                                  const float* __restrict__ W,
                                                  const float* __restrict__ bias,
                                                  const float* __restrict__ attn,
                                                  float* __restrict__ h1, int M) {
    __shared__ float As[64][IN_DIM + 4];
    __shared__ float Bs[32][HID_DIM];
    const int t = threadIdx.x;
    const int row0 = blockIdx.x * 64;
    const int col = t & 63;         // *4 -> cols
    const int rbase = (t >> 6) * 8; // wave-uniform, waves 0..7 -> rows 0..56

    #pragma unroll
    for (int i = 0; i < 4; ++i) {
        int idx = t + i * 512;          // 0..2047 float4 slots (64 rows x 32 f4)
        int r = idx >> 5, c4 = idx & 31;
        int row = row0 + r;
        float4 v = make_float4(0.f, 0.f, 0.f, 0.f);
        if (row < M) v = ((const float4*)(agg + (size_t)row * IN_DIM))[c4];
        *(float4*)&As[r][c4 * 4] = v;
    }

    float4 acc[8];
    #pragma unroll
    for (int rr = 0; rr < 8; ++rr) acc[rr] = make_float4(0.f, 0.f, 0.f, 0.f);

    for (int kc = 0; kc < 4; ++kc) {   // K chunks of 32
        __syncthreads();
        #pragma unroll
        for (int i = 0; i < 4; ++i) {
            int idx = t + i * 512;      // 0..2047 float4 slots (32x64)
            int kk = idx >> 6, c4 = idx & 63;
            *(float4*)&Bs[kk][c4 * 4] = ((const float4*)(W + (size_t)(kc * 32 + kk) * HID_DIM))[c4];
        }
        __syncthreads();
        #pragma unroll 2
        for (int k4 = 0; k4 < 8; ++k4) {
            int kk = k4 * 4;
            float4 b0 = *(float4*)&Bs[kk + 0][col * 4];
            float4 b1v = *(float4*)&Bs[kk + 1][col * 4];
            float4 b2v = *(float4*)&Bs[kk + 2][col * 4];
            float4 b3v = *(float4*)&Bs[kk + 3][col * 4];
            int ka = kc * 32 + kk;
            #pragma unroll
            for (int rr = 0; rr < 8; ++rr) {
                float4 a = *(const float4*)&As[rbase + rr][ka];
                acc[rr].x += a.x * b0.x + a.y * b1v.x + a.z * b2v.x + a.w * b3v.x;
                acc[rr].y += a.x * b0.y + a.y * b1v.y + a.z * b2v.y + a.w * b3v.y;
                acc[rr].z += a.x * b0.z + a.y * b1v.z + a.z * b2v.z + a.w * b3v.z;
                acc[rr].w += a.x * b0.w + a.y * b1v.w + a.z * b2v.w + a.w * b3v.w;
            }
        }
    }

    float4 bb = *(const float4*)&bias[col * 4];
    float4 at = *(const float4*)&attn[col * 4];
    #pragma unroll
    for (int rr = 0; rr < 8; ++rr) {
        int row = row0 + rbase + rr;
        float4 v = acc[rr];
        v.x += bb.x; v.y += bb.y; v.z += bb.z; v.w += bb.w;
        float p = v.x * at.x + v.y * at.y + v.z * at.z + v.w * at.w;
        p += __shfl_down(p, 32);
        p += __shfl_down(p, 16);
        p += __shfl_down(p, 8);
        p += __shfl_down(p, 4);
        p += __shfl_down(p, 2);
        p += __shfl_down(p, 1);
        p = __shfl(p, 0);
        float alpha = 1.f / (1.f + expf(-p));
        v.x *= alpha; v.y *= alpha; v.z *= alpha; v.w *= alpha;
        if (row < M) *(float4*)&h1[(size_t)row * HID_DIM + col * 4] = v;
    }
}

// ---------------- GEMM2 + bias + sigmoid gate -> outputs ----------------
__global__ __launch_bounds__(256) void gemm2_gate(const float* __restrict__ agg,
                                                  const float* __restrict__ W,
                                                  const float* __restrict__ bias,
                                                  const float* __restrict__ attn,
                                                  float* __restrict__ out_h,
                                                  float* __restrict__ out_alpha, int M) {
    __shared__ float As[32][HID_DIM + 4];
    __shared__ float Bs[32][OUT_DIM];
    const int t = threadIdx.x;
    const int row0 = blockIdx.x * 32;
    const int col = t & 63;         // *2 -> cols
    const int rbase = (t >> 6) * 8; // wave-uniform

    #pragma unroll
    for (int i = 0; i < 8; ++i) {
        int idx = t + i * 256;       // 0..2047 float4 slots (32x64)
        int r = idx >> 6, c4 = idx & 63;
        int row = row0 + r;
        float4 v = make_float4(0.f, 0.f, 0.f, 0.f);
        if (row < M) v = ((const float4*)(agg + (size_t)row * HID_DIM))[c4];
        *(float4*)&As[r][c4 * 4] = v;
    }

    float2 acc[8];
    #pragma unroll
    for (int rr = 0; rr < 8; ++rr) acc[rr] = make_float2(0.f, 0.f);

    for (int kc = 0; kc < 8; ++kc) {   // K=256, chunks of 32
        __syncthreads();
        #pragma unroll
        for (int i = 0; i < 4; ++i) {
            int idx = t + i * 256;      // 0..1023 float4 slots (32x32)
            int kk = idx >> 5, c4 = idx & 31;
            *(float4*)&Bs[kk][c4 * 4] = ((const float4*)(W + (size_t)(kc * 32 + kk) * OUT_DIM))[c4];
        }
        __syncthreads();
        #pragma unroll
        for (int k4 = 0; k4 < 8; ++k4) {
            int kk = k4 * 4;
            float2 b0 = *(float2*)&Bs[kk + 0][col * 2];
            float2 b1v = *(float2*)&Bs[kk + 1][col * 2];
            float2 b2v = *(float2*)&Bs[kk + 2][col * 2];
            float2 b3v = *(float2*)&Bs[kk + 3][col * 2];
            int ka = kc * 32 + kk;
            #pragma unroll
            for (int rr = 0; rr < 8; ++rr) {
                float4 a = *(const float4*)&As[rbase + rr][ka];
                acc[rr].x += a.x * b0.x + a.y * b1v.x + a.z * b2v.x + a.w * b3v.x;
                acc[rr].y += a.x * b0.y + a.y * b1v.y + a.z * b2v.y + a.w * b3v.y;
            }
        }
    }

    float2 bb = *(const float2*)&bias[col * 2];
    float2 at = *(const float2*)&attn[col * 2];
    #pragma unroll
    for (int rr = 0; rr < 8; ++rr) {
        int row = row0 + rbase + rr;
        float2 v = acc[rr];
        v.x += bb.x; v.y += bb.y;
        float p = v.x * at.x + v.y * at.y;
        p += __shfl_down(p, 32);
        p += __shfl_down(p, 16);
        p += __shfl_down(p, 8);
        p += __shfl_down(p, 4);
        p += __shfl_down(p, 2);
        p += __shfl_down(p, 1);
        p = __shfl(p, 0);
        float alpha = 1.f / (1.f + expf(-p));
        v.x *= alpha; v.y *= alpha;
        if (row < M) {
            *(float2*)&out_h[(size_t)row * OUT_DIM + col * 2] = v;
            if (col == 0) out_alpha[row] = alpha;
        }
    }
}

extern "C" void kernel_launch(void* const* d_in, const int* in_sizes, int n_in,
                              void* d_out, int out_size, void* d_ws, size_t ws_size,
                              hipStream_t stream) {
    const float* feat  = (const float*)d_in[0];
    const float* W1    = (const float*)d_in[1];
    const float* b1    = (const float*)d_in[2];
    const float* attn1 = (const float*)d_in[3];
    const float* W2    = (const float*)d_in[4];
    const float* b2    = (const float*)d_in[5];
    const float* attn2 = (const float*)d_in[6];
    const int* src1 = (const int*)d_in[7];
    const int* dst1 = (const int*)d_in[8];
    const int* src2 = (const int*)d_in[9];
    const int* dst2 = (const int*)d_in[10];
    float* out = (float*)d_out;

    // workspace layout
    float* ws = (float*)d_ws;
    float* outdeg1 = ws;                                   // N_SRC1 (zeroed)
    float* outdeg2 = outdeg1 + N_SRC1;                     // N_SRC2 (zeroed)
    int*   cnt1    = (int*)(outdeg2 + N_SRC2);             // N_DST1 (zeroed)
    int*   cnt2    = cnt1 + N_DST1;                        // N_DST2 (zeroed)
    int*   offs1   = cnt2 + N_DST2;                        // N_DST1+1
    int*   cursor1 = offs1 + N_DST1 + 1;                   // N_DST1
    int*   offs2   = cursor1 + N_DST1;                     // N_DST2+1
    int*   cursor2 = offs2 + N_DST2 + 1;                   // N_DST2
    int*   elist1  = cursor2 + N_DST2;                     // E1
    int*   elist2  = elist1 + E1;                          // E2
    float* agg1    = (float*)(elist2 + E2);                // N_DST1*IN_DIM
    float* agg2    = agg1 + (size_t)N_DST1 * IN_DIM;       // N_DST2*HID_DIM
    float* h1      = agg2 + (size_t)N_DST2 * HID_DIM;      // N_DST1*HID_DIM
    int*   bsum1   = (int*)(h1 + (size_t)N_DST1 * HID_DIM); // 128 block sums
    int*   bsum2   = bsum1 + 128;                          // 16 block sums

    // zero only the atomic-accumulated arrays (outdeg1, outdeg2, cnt1, cnt2 contiguous)
    const size_t zero_bytes = ((size_t)N_SRC1 + N_SRC2 + N_DST1 + N_DST2) * 4;
    hipMemsetAsync(d_ws, 0, zero_bytes, stream);

    count_kernel<<<(E1 + 255) / 256, 256, 0, stream>>>(src1, dst1, outdeg1, cnt1, E1);
    count_kernel<<<(E2 + 255) / 256, 256, 0, stream>>>(src2, dst2, outdeg2, cnt2, E2);
    rsqrt_kernel<<<(N_SRC1 + N_SRC2 + 255) / 256, 256, 0, stream>>>(outdeg1, N_SRC1 + N_SRC2);

    // device-wide 3-phase scans
    const int nb1 = (N_DST1 + 1023) / 1024;   // 108
    const int nb2 = (N_DST2 + 1023) / 1024;   // 10
    scan_part<<<nb1, 1024, 0, stream>>>(cnt1, offs1, bsum1, N_DST1);
    scan_bsum<<<1, 1024, 0, stream>>>(bsum1, offs1 + N_DST1, nb1);
    scan_add<<<nb1, 1024, 0, stream>>>(offs1, cursor1, bsum1, N_DST1);
    scan_part<<<nb2, 1024, 0, stream>>>(cnt2, offs2, bsum2, N_DST2);
    scan_bsum<<<1, 1024, 0, stream>>>(bsum2, offs2 + N_DST2, nb2);
    scan_add<<<nb2, 1024, 0, stream>>>(offs2, cursor2, bsum2, N_DST2);

    fill_kernel<<<(E1 + 255) / 256, 256, 0, stream>>>(src1, dst1, cursor1, elist1, E1);
    fill_kernel<<<(E2 + 255) / 256, 256, 0, stream>>>(src2, dst2, cursor2, elist2, E2);

    gather1_kernel<<<(N_DST1 + 3) / 4, 256, 0, stream>>>(feat, elist1, offs1, outdeg1, agg1, N_DST1);
    gemm1_gate<<<(N_DST1 + 63) / 64, 512, 0, stream>>>(agg1, W1, b1, attn1, h1, N_DST1);
    gather2_kernel<<<(N_DST2 + 3) / 4, 256, 0, stream>>>(h1, elist2, offs2, outdeg2, agg2, N_DST2);
    gemm2_gate<<<(N_DST2 + 31) / 32, 256, 0, stream>>>(agg2, W2, b2, attn2,
                                                       out, out + (size_t)N_DST2 * OUT_DIM, N_DST2);
}